// Round 1
// baseline (145.106 us; speedup 1.0000x reference)
//
#include <hip/hip_runtime.h>

#define BB 8
#define NN 128
#define ND 64
#define LL 512
#define RD 1024
#define CG 128
#define CP 128
#define HID 192

// ---------------------------------------------------------------------------
// K1: h0 = nodes @ Wn + bn ; norm = rsqrt(max(deg,1)) ; prep block computes
//     v = W2 @ Wo (192), cconst = N*L*(b2@Wo) + bo, zeroes acc[8].
// grid 257 x 256
// ---------------------------------------------------------------------------
__global__ __launch_bounds__(256) void k1_h0_norm_prep(
    const float* __restrict__ adj, const float* __restrict__ nodes,
    const float* __restrict__ Wn, const float* __restrict__ bn,
    const float* __restrict__ W2, const float* __restrict__ b2,
    const float* __restrict__ Wo, const float* __restrict__ bo,
    float* __restrict__ hA, float* __restrict__ normb,
    float* __restrict__ vbuf, float* __restrict__ cconst,
    float* __restrict__ acc)
{
    int t = threadIdx.x;
    int blk = blockIdx.x;
    if (blk == 256) {
        if (t < HID) {
            float s = 0.f;
            for (int k = 0; k < CG; ++k) s = fmaf(W2[t * CG + k], Wo[k], s);
            vbuf[t] = s;
        }
        if (t == 255) {
            float s = 0.f;
            for (int k = 0; k < CG; ++k) s = fmaf(b2[k], Wo[k], s);
            cconst[0] = (float)(NN * LL) * s + bo[0];
        }
        if (t < BB) acc[t] = 0.f;
        return;
    }
    int b = blk >> 5;           // 32 blocks per batch
    int n0 = (blk & 31) * 4;    // 4 rows per block
    __shared__ float sn[4][ND];
    sn[t >> 6][t & 63] = nodes[(b * NN + n0 + (t >> 6)) * ND + (t & 63)];
    __syncthreads();
    // degree via one wave per row
    {
        int w = t >> 6, lane = t & 63;
        const float* ar = adj + (size_t)(b * NN + n0 + w) * NN;
        float d = ar[lane] + ar[lane + 64];
        for (int off = 32; off; off >>= 1) d += __shfl_down(d, off);
        if (lane == 0) normb[b * NN + n0 + w] = rsqrtf(fmaxf(d, 1.0f));
    }
    // h0: 4 rows x 128 cols, 2 outputs per thread
    int c = t & 127, rr = t >> 7;   // rows rr and rr+2
    float a0 = bn[c], a1 = bn[c];
    for (int k = 0; k < ND; ++k) {
        float wv = Wn[k * CG + c];
        a0 = fmaf(sn[rr][k], wv, a0);
        a1 = fmaf(sn[rr + 2][k], wv, a1);
    }
    hA[(b * NN + n0 + rr) * CG + c] = a0;
    hA[(b * NN + n0 + rr + 2) * CG + c] = a1;
}

// ---------------------------------------------------------------------------
// K2: one GNN step: hnew = act( (adj @ (h*norm)) * norm @ Wg + bg )
// MODE 0: relu, store hout. MODE 1: tanh, then hW1 = h @ W1_top + b1.
// grid B*16 (8 rows/block) x 256
// ---------------------------------------------------------------------------
template <int MODE>
__global__ __launch_bounds__(256) void k2_gnn(
    const float* __restrict__ adj, const float* __restrict__ hin,
    const float* __restrict__ Wg, const float* __restrict__ bg,
    const float* __restrict__ normb, float* __restrict__ hout,
    const float* __restrict__ W1, const float* __restrict__ b1,
    float* __restrict__ hW1)
{
    int t = threadIdx.x;
    int b = blockIdx.x >> 4;
    int i0 = (blockIdx.x & 15) * 8;
    __shared__ float hs[64][CG];    // 32KB, staged half of h*norm
    __shared__ float ms[8][CG];     // 4KB
    int c = t & 127;
    int ib = (t >> 7) * 4;          // 0 or 4
    float m[4] = {0.f, 0.f, 0.f, 0.f};
    const float* hbase = hin + (size_t)b * NN * CG;
    for (int half = 0; half < 2; ++half) {
        __syncthreads();
        #pragma unroll
        for (int q = 0; q < 8; ++q) {
            int f4 = t + 256 * q;        // 0..2047
            int row = f4 >> 5;           // 0..63
            int col4 = (f4 & 31) * 4;
            float4 hv = *(const float4*)(hbase + (half * 64 + row) * CG + col4);
            float nv = normb[b * NN + half * 64 + row];
            hv.x *= nv; hv.y *= nv; hv.z *= nv; hv.w *= nv;
            *(float4*)(&hs[row][col4]) = hv;
        }
        __syncthreads();
        const float* arow = adj + (size_t)(b * NN + i0 + ib) * NN + half * 64;
        for (int j = 0; j < 64; ++j) {
            float hv = hs[j][c];
            float a0 = arow[0 * NN + j];
            float a1 = arow[1 * NN + j];
            float a2 = arow[2 * NN + j];
            float a3 = arow[3 * NN + j];
            m[0] = fmaf(a0, hv, m[0]);
            m[1] = fmaf(a1, hv, m[1]);
            m[2] = fmaf(a2, hv, m[2]);
            m[3] = fmaf(a3, hv, m[3]);
        }
    }
    #pragma unroll
    for (int k = 0; k < 4; ++k)
        ms[ib + k][c] = m[k] * normb[b * NN + i0 + ib + k];
    __syncthreads();
    float acc2[4];
    #pragma unroll
    for (int k = 0; k < 4; ++k) acc2[k] = bg[c];
    for (int k = 0; k < CG; ++k) {
        float wv = Wg[k * CG + c];
        acc2[0] = fmaf(ms[ib + 0][k], wv, acc2[0]);
        acc2[1] = fmaf(ms[ib + 1][k], wv, acc2[1]);
        acc2[2] = fmaf(ms[ib + 2][k], wv, acc2[2]);
        acc2[3] = fmaf(ms[ib + 3][k], wv, acc2[3]);
    }
    if (MODE == 0) {
        #pragma unroll
        for (int k = 0; k < 4; ++k)
            hout[(size_t)(b * NN + i0 + ib + k) * CG + c] = fmaxf(acc2[k], 0.f);
    } else {
        float* hn = &hs[0][0];   // reuse (8*128 floats)
        #pragma unroll
        for (int k = 0; k < 4; ++k)
            hn[(ib + k) * CG + c] = tanhf(acc2[k]);
        __syncthreads();
        // hW1: 8 rows x 192 = 1536 outputs, 6 per thread; b1 folded here
        #pragma unroll
        for (int q = 0; q < 6; ++q) {
            int out = t + 256 * q;
            int i = out / HID, jj = out % HID;
            float s = b1[jj];
            for (int k = 0; k < CG; ++k)
                s = fmaf(hn[i * CG + k], W1[k * HID + jj], s);
            hW1[(size_t)(b * NN + i0 + i) * HID + jj] = s;
        }
    }
}

// ---------------------------------------------------------------------------
// K3: rW1[b,l,:] = (prot[b,l,:] @ Wr + br) @ W1_bot   (no bias; b1 in hW1)
// grid B*32 (16 rows/block) x 256
// ---------------------------------------------------------------------------
__global__ __launch_bounds__(256) void k3_rW1(
    const float* __restrict__ prot, const float* __restrict__ Wr,
    const float* __restrict__ br, const float* __restrict__ W1,
    float* __restrict__ rW1)
{
    int t = threadIdx.x;
    int b = blockIdx.x >> 5;
    int l0 = (blockIdx.x & 31) * 16;
    __shared__ float sbuf[16 * 132];   // chunk staging / r tile (padded stride)
    int c0 = t & 63;
    int ib = (t >> 6) * 4;             // rows ib..ib+3
    float r[4][2] = {};
    const float* pbase = prot + ((size_t)b * LL + l0) * RD;
    for (int k0 = 0; k0 < RD; k0 += 128) {
        __syncthreads();
        #pragma unroll
        for (int h = 0; h < 2; ++h) {
            int f4 = t + 256 * h;        // 0..511
            int row = f4 >> 5;           // 0..15
            int col4 = (f4 & 31) * 4;
            float4 pv = *(const float4*)(pbase + (size_t)row * RD + k0 + col4);
            *(float4*)(&sbuf[row * 132 + col4]) = pv;
        }
        __syncthreads();
        for (int kk = 0; kk < 128; kk += 4) {
            float4 p0 = *(const float4*)(&sbuf[(ib + 0) * 132 + kk]);
            float4 p1 = *(const float4*)(&sbuf[(ib + 1) * 132 + kk]);
            float4 p2 = *(const float4*)(&sbuf[(ib + 2) * 132 + kk]);
            float4 p3 = *(const float4*)(&sbuf[(ib + 3) * 132 + kk]);
            const float* pp0 = (const float*)&p0;
            const float* pp1 = (const float*)&p1;
            const float* pp2 = (const float*)&p2;
            const float* pp3 = (const float*)&p3;
            #pragma unroll
            for (int q = 0; q < 4; ++q) {
                float w0 = Wr[(size_t)(k0 + kk + q) * CG + c0];
                float w1 = Wr[(size_t)(k0 + kk + q) * CG + c0 + 64];
                r[0][0] = fmaf(pp0[q], w0, r[0][0]);
                r[0][1] = fmaf(pp0[q], w1, r[0][1]);
                r[1][0] = fmaf(pp1[q], w0, r[1][0]);
                r[1][1] = fmaf(pp1[q], w1, r[1][1]);
                r[2][0] = fmaf(pp2[q], w0, r[2][0]);
                r[2][1] = fmaf(pp2[q], w1, r[2][1]);
                r[3][0] = fmaf(pp3[q], w0, r[3][0]);
                r[3][1] = fmaf(pp3[q], w1, r[3][1]);
            }
        }
    }
    __syncthreads();
    #pragma unroll
    for (int i = 0; i < 4; ++i) {
        sbuf[(ib + i) * 132 + c0]      = r[i][0] + br[c0];
        sbuf[(ib + i) * 132 + c0 + 64] = r[i][1] + br[c0 + 64];
    }
    __syncthreads();
    // stage 2: rW1 = rtile @ W1_bot. 16*192 outs as 768 float4-quads, 3/thread
    const float* W1b = W1 + CG * HID;
    #pragma unroll
    for (int q = 0; q < 3; ++q) {
        int quad = t + 256 * q;          // 0..767
        int i = quad / 48, j4 = (quad % 48) * 4;
        float4 s = {0.f, 0.f, 0.f, 0.f};
        for (int k = 0; k < CG; ++k) {
            float rv = sbuf[i * 132 + k];
            float4 wv = *(const float4*)(&W1b[k * HID + j4]);
            s.x = fmaf(rv, wv.x, s.x);
            s.y = fmaf(rv, wv.y, s.y);
            s.z = fmaf(rv, wv.z, s.z);
            s.w = fmaf(rv, wv.w, s.w);
        }
        *(float4*)(&rW1[((size_t)b * LL + l0 + i) * HID + j4]) = s;
    }
}

// ---------------------------------------------------------------------------
// K4: acc[b] += sum_{n,l} v . relu(hW1[b,n,:] + rW1[b,l,:])
// grid B*8(nsplit)*8(ltile) = 512 x 256 ; wave owns j-quarter, lane owns l
// ---------------------------------------------------------------------------
__global__ __launch_bounds__(256) void k4_pairsum(
    const float* __restrict__ hW1, const float* __restrict__ rW1,
    const float* __restrict__ vbuf, float* __restrict__ acc)
{
    int t = threadIdx.x;
    int blk = blockIdx.x;
    int b = blk >> 6;
    int ns = (blk >> 3) & 7;    // n range: 16 rows
    int lt = blk & 7;           // l tile: 64
    int wv = t >> 6;            // j-quarter (48 dims)
    int lane = t & 63;
    int j0 = wv * 48;
    int l = lt * 64 + lane;
    float r[48], v[48];
    const float* rp = rW1 + ((size_t)b * LL + l) * HID + j0;
    const float* vp = vbuf + j0;
    #pragma unroll
    for (int q = 0; q < 12; ++q) {
        float4 f = *(const float4*)(rp + q * 4);
        r[q * 4 + 0] = f.x; r[q * 4 + 1] = f.y; r[q * 4 + 2] = f.z; r[q * 4 + 3] = f.w;
    }
    #pragma unroll
    for (int q = 0; q < 12; ++q) {
        float4 f = *(const float4*)(vp + q * 4);
        v[q * 4 + 0] = f.x; v[q * 4 + 1] = f.y; v[q * 4 + 2] = f.z; v[q * 4 + 3] = f.w;
    }
    float a0 = 0.f, a1 = 0.f, a2 = 0.f, a3 = 0.f;
    const float* hp = hW1 + ((size_t)b * NN + ns * 16) * HID + j0;
    for (int n = 0; n < 16; ++n) {
        float hv[48];
        #pragma unroll
        for (int q = 0; q < 12; ++q) {
            float4 f = *(const float4*)(hp + n * HID + q * 4);
            hv[q * 4 + 0] = f.x; hv[q * 4 + 1] = f.y; hv[q * 4 + 2] = f.z; hv[q * 4 + 3] = f.w;
        }
        #pragma unroll
        for (int j = 0; j < 48; j += 4) {
            a0 = fmaf(v[j + 0], fmaxf(hv[j + 0] + r[j + 0], 0.f), a0);
            a1 = fmaf(v[j + 1], fmaxf(hv[j + 1] + r[j + 1], 0.f), a1);
            a2 = fmaf(v[j + 2], fmaxf(hv[j + 2] + r[j + 2], 0.f), a2);
            a3 = fmaf(v[j + 3], fmaxf(hv[j + 3] + r[j + 3], 0.f), a3);
        }
    }
    float a = (a0 + a1) + (a2 + a3);
    for (int off = 32; off; off >>= 1) a += __shfl_down(a, off);
    __shared__ float sred[4];
    if (lane == 0) sred[wv] = a;
    __syncthreads();
    if (t == 0) atomicAdd(&acc[b], (sred[0] + sred[1]) + (sred[2] + sred[3]));
}

// ---------------------------------------------------------------------------
// K5: out[b] = acc[b] + cconst
// ---------------------------------------------------------------------------
__global__ __launch_bounds__(64) void k5_final(
    const float* __restrict__ acc, const float* __restrict__ cconst,
    float* __restrict__ out)
{
    int t = threadIdx.x;
    if (t < BB) out[t] = acc[t] + cconst[0];
}

extern "C" void kernel_launch(void* const* d_in, const int* in_sizes, int n_in,
                              void* d_out, int out_size, void* d_ws, size_t ws_size,
                              hipStream_t stream)
{
    const float* adj   = (const float*)d_in[0];
    const float* nodes = (const float*)d_in[1];
    const float* prot  = (const float*)d_in[2];
    const float* Wn    = (const float*)d_in[3];
    const float* bn    = (const float*)d_in[4];
    const float* Wg    = (const float*)d_in[5];
    const float* bg    = (const float*)d_in[6];
    const float* Wr    = (const float*)d_in[7];
    const float* br    = (const float*)d_in[8];
    // d_in[9]=Wa, d_in[10]=ba: unused (softmax over size-1 axis == 1)
    const float* W1    = (const float*)d_in[11];
    const float* b1    = (const float*)d_in[12];
    const float* W2    = (const float*)d_in[13];
    const float* b2    = (const float*)d_in[14];
    const float* Wo    = (const float*)d_in[15];
    const float* bo    = (const float*)d_in[16];

    float* ws     = (float*)d_ws;
    float* hA     = ws;                       // [8][128][128]
    float* hB     = hA + BB * NN * CG;        // [8][128][128]
    float* normb  = hB + BB * NN * CG;        // [8][128]
    float* hW1b   = normb + BB * NN;          // [8][128][192]
    float* rW1b   = hW1b + BB * NN * HID;     // [8][512][192]
    float* vbuf   = rW1b + BB * LL * HID;     // [192]
    float* cconst = vbuf + HID;               // [1]
    float* accb   = cconst + 1;               // [8]
    float* out    = (float*)d_out;

    // K3 first (longest, independent of GNN chain)
    hipLaunchKernelGGL(k3_rW1, dim3(256), dim3(256), 0, stream, prot, Wr, br, W1, rW1b);
    hipLaunchKernelGGL(k1_h0_norm_prep, dim3(257), dim3(256), 0, stream,
                       adj, nodes, Wn, bn, W2, b2, Wo, bo, hA, normb, vbuf, cconst, accb);
    hipLaunchKernelGGL(k2_gnn<0>, dim3(BB * 16), dim3(256), 0, stream,
                       adj, hA, Wg, bg, normb, hB, W1, b1, hW1b);
    hipLaunchKernelGGL(k2_gnn<0>, dim3(BB * 16), dim3(256), 0, stream,
                       adj, hB, Wg, bg, normb, hA, W1, b1, hW1b);
    hipLaunchKernelGGL(k2_gnn<1>, dim3(BB * 16), dim3(256), 0, stream,
                       adj, hA, Wg, bg, normb, hB, W1, b1, hW1b);
    hipLaunchKernelGGL(k4_pairsum, dim3(512), dim3(256), 0, stream, hW1b, rW1b, vbuf, accb);
    hipLaunchKernelGGL(k5_final, dim3(1), dim3(64), 0, stream, accb, cconst, out);
}